// Round 1
// baseline (582.658 us; speedup 1.0000x reference)
//
#include <hip/hip_runtime.h>
#include <stdint.h>

// Problem constants
#define B_   8
#define C_   256
#define N_   16384   // 128*128 spatial

typedef __attribute__((ext_vector_type(8))) short bf16x8;
typedef __attribute__((ext_vector_type(4))) float f32x4;

__device__ inline unsigned short f2bf(float f) {
    unsigned u = __float_as_uint(f);
    u += 0x7FFF + ((u >> 16) & 1);   // round-to-nearest-even
    return (unsigned short)(u >> 16);
}

// async global->LDS, 16B per lane. LDS dest = wave-uniform base + lane*16.
__device__ inline void gl_lds16(const void* g, void* l) {
    __builtin_amdgcn_global_load_lds(
        reinterpret_cast<const __attribute__((address_space(1))) unsigned int*>(
            reinterpret_cast<uintptr_t>(g)),
        reinterpret_cast<__attribute__((address_space(3))) unsigned int*>(
            reinterpret_cast<uintptr_t>(l)),
        16, 0, 0);
}

__device__ inline f32x4 mfma16(bf16x8 a, bf16x8 b, f32x4 c) {
    return __builtin_amdgcn_mfma_f32_16x16x32_bf16(a, b, c, 0, 0, 0);
}

// ---------------------------------------------------------------------------
// K1: x [B,C,N] fp32  ->  xT [B,N,C] bf16   (64x64 tiles through LDS)
// ---------------------------------------------------------------------------
__global__ __launch_bounds__(256) void k1_transpose(const float* __restrict__ x,
                                                    unsigned short* __restrict__ xT) {
    __shared__ unsigned short tile[64][65];
    const int b = blockIdx.z, c0 = blockIdx.y * 64, n0 = blockIdx.x * 64;
    const float* xb = x + (size_t)b * C_ * N_;
    const int t = threadIdx.x;
    const int tr = t >> 4, tc4 = (t & 15) * 4;
#pragma unroll
    for (int p = 0; p < 4; p++) {
        const int i = p * 16 + tr;   // c index
        const float4 v = *(const float4*)(xb + (size_t)(c0 + i) * N_ + n0 + tc4);
        tile[i][tc4 + 0] = f2bf(v.x);
        tile[i][tc4 + 1] = f2bf(v.y);
        tile[i][tc4 + 2] = f2bf(v.z);
        tile[i][tc4 + 3] = f2bf(v.w);
    }
    __syncthreads();
    unsigned short* xTb = xT + (size_t)b * N_ * C_;
#pragma unroll
    for (int p = 0; p < 4; p++) {
        const int jj = p * 16 + tr;  // n index
        ushort4 o;
        o.x = tile[tc4 + 0][jj];
        o.y = tile[tc4 + 1][jj];
        o.z = tile[tc4 + 2][jj];
        o.w = tile[tc4 + 3][jj];
        *(ushort4*)(xTb + (size_t)(n0 + jj) * C_ + c0 + tc4) = o;
    }
}

// ---------------------------------------------------------------------------
// K1b: blocks 0..63: pack w_kv (wqkv rows 256..767) into fragment-major bf16:
//      WkvF[((rowblk*8 + kblk)*64 + lane)*8 + e] = wkv[rowblk*16 + (lane&15),
//                                                      kblk*32 + (lane>>4)*8 + e]
//      block 64: BN constants.
// ---------------------------------------------------------------------------
__global__ __launch_bounds__(256) void k1b_setup(const float* __restrict__ wqkv,
                                                 const float* __restrict__ gamma,
                                                 const float* __restrict__ beta,
                                                 const float* __restrict__ rmean,
                                                 const float* __restrict__ rvar,
                                                 unsigned short* __restrict__ WkvF,
                                                 float* __restrict__ inv,
                                                 float* __restrict__ b2) {
    const int t = threadIdx.x;
    if (blockIdx.x < 64) {
        const int chunk = blockIdx.x * 256 + t;   // 16384 chunks of 8 shorts
        const int lane = chunk & 63;
        const int kb = (chunk >> 6) & 7;
        const int rb = chunk >> 9;                // 0..31
        const int row = rb * 16 + (lane & 15);    // 0..511 (kv row)
        const int k0 = kb * 32 + (lane >> 4) * 8;
        const float* src = wqkv + (size_t)(256 + row) * 256 + k0;
        const float4 a = *(const float4*)(src);
        const float4 c = *(const float4*)(src + 4);
        ushort4 o0, o1;
        o0.x = f2bf(a.x); o0.y = f2bf(a.y); o0.z = f2bf(a.z); o0.w = f2bf(a.w);
        o1.x = f2bf(c.x); o1.y = f2bf(c.y); o1.z = f2bf(c.z); o1.w = f2bf(c.w);
        *(ushort4*)(WkvF + (size_t)chunk * 8) = o0;
        *(ushort4*)(WkvF + (size_t)chunk * 8 + 4) = o1;
    } else {
        const float iv = gamma[t] * rsqrtf(rvar[t] + 1e-5f);
        inv[t] = iv;
        b2[t]  = beta[t] - rmean[t] * iv;
    }
}

// ---------------------------------------------------------------------------
// K2: FUSED kv-GEMM + exp (shift-free softmax numerator) + context GEMM.
//  Per block: batch b, n-chunk of 512. Loop 8 subchunks of 64 n:
//    stage xT[64n,256c] -> LDS (double-buffered, src-swizzled for gl_lds16),
//    kv[512,64] = Wkv @ x  (A-frags streamed from L2 fragment-major layout),
//    exp() on k half (rows 0..255) + in-register rsum partials,
//    kv -> swizzled LDS,  ctx[256,256] += expk @ v^T  (acc in registers).
//  Epilogue: atomicAdd ctx + rsum.
//  grid (32 chunks, 8 batches), 512 threads (8 waves). LDS = 128 KiB.
// ---------------------------------------------------------------------------
__global__ __launch_bounds__(512, 2) void k2_ctx(const unsigned short* __restrict__ WkvF,
                                                 const unsigned short* __restrict__ xT,
                                                 float* __restrict__ ctx,
                                                 float* __restrict__ rsum) {
    __shared__ __align__(16) unsigned short xs[2][64 * 256];   // 2 x 32 KiB
    __shared__ __align__(16) unsigned short kvs[512 * 64];     // 64 KiB
    const int b  = blockIdx.y;
    const int n0 = blockIdx.x * 512;
    const int t = threadIdx.x, wave = t >> 6, lane = t & 63;
    const int fr = lane & 15, fkq = lane >> 4;                 // frag row / k-quad
    const int wr = wave >> 1, wc = wave & 1;                   // ctx wave grid 4x2
    const unsigned short* xTb = xT + (size_t)b * N_ * C_;

    f32x4 acc[4][8];                 // ctx tile 64c x 128d per wave
#pragma unroll
    for (int i = 0; i < 4; i++)
#pragma unroll
        for (int j = 0; j < 8; j++)
#pragma unroll
            for (int r = 0; r < 4; r++) acc[i][j][r] = 0.f;
    float rsacc[2][4];               // row-sum partials for pass-0 rows
#pragma unroll
    for (int i = 0; i < 2; i++)
#pragma unroll
        for (int r = 0; r < 4; r++) rsacc[i][r] = 0.f;

    // stage subchunk sc (64 n-rows x 256 c) into xs[buf]; LDS is linear,
    // global source columns inverse-swizzled: LDS[r][cc] = xT[nb+r][cc ^ ((r&7)*8)]
    auto stage = [&](int buf, int sc) {
        const int nb = n0 + sc * 64;
#pragma unroll
        for (int it = 0; it < 4; it++) {
            const int idx = it * 512 + t;        // 16B-chunk id, 0..2047
            const int r = idx >> 5;              // n row 0..63
            const int c = (idx & 31) * 8;        // c col (short units)
            const int csw = c ^ ((r & 7) * 8);
            gl_lds16(xTb + (size_t)(nb + r) * 256 + csw,
                     &xs[buf][it * 4096 + wave * 512]);
        }
    };

    stage(0, 0);
    __syncthreads();

    for (int s = 0; s < 8; ++s) {
        const int cur = s & 1;
        if (s < 7) stage(cur ^ 1, s + 1);        // prefetch next subchunk

        // GEMM1 in two passes of 32 kv-rows/wave: p=0 -> k rows 0..255 (exp),
        // p=1 -> v rows 256..511
#pragma unroll
        for (int p = 0; p < 2; ++p) {
            f32x4 kacc[2][4];
#pragma unroll
            for (int i = 0; i < 2; i++)
#pragma unroll
                for (int j = 0; j < 4; j++)
#pragma unroll
                    for (int r = 0; r < 4; r++) kacc[i][j][r] = 0.f;
#pragma unroll
            for (int kb = 0; kb < 8; kb++) {
                bf16x8 bfv[4];
#pragma unroll
                for (int j = 0; j < 4; j++) {
                    const int rr = j * 16 + fr;
                    const int cs = (kb * 32 + fkq * 8) ^ ((rr & 7) * 8);
                    bfv[j] = *(const bf16x8*)(&xs[cur][rr * 256 + cs]);
                }
#pragma unroll
                for (int i = 0; i < 2; i++) {
                    const int rb = p * 16 + 2 * wave + i;   // rowblk
                    const bf16x8 af = *(const bf16x8*)(
                        WkvF + (((size_t)rb * 8 + kb) * 64 + lane) * 8);
#pragma unroll
                    for (int j = 0; j < 4; j++)
                        kacc[i][j] = mfma16(af, bfv[j], kacc[i][j]);
                }
            }
            // exp (pass 0) + write to swizzled kvs
#pragma unroll
            for (int i = 0; i < 2; i++) {
                const int rowb = p * 256 + 32 * wave + i * 16 + fkq * 4;
#pragma unroll
                for (int j = 0; j < 4; j++) {
                    const int cn = j * 16 + fr;
#pragma unroll
                    for (int r = 0; r < 4; r++) {
                        float vv = kacc[i][j][r];
                        if (p == 0) { vv = __expf(vv); rsacc[i][r] += vv; }
                        const int row = rowb + r;
                        kvs[row * 64 + (cn ^ ((row & 7) * 8))] = f2bf(vv);
                    }
                }
            }
        }
        __syncthreads();   // kvs complete (also drains prefetch vmcnt)

        // GEMM2: ctx[64c x 128d] += expk[64c x 64n] * v[128d x 64n]^T
#pragma unroll
        for (int kk = 0; kk < 2; kk++) {
            bf16x8 a2[4], b2v[8];
#pragma unroll
            for (int i = 0; i < 4; i++) {
                const int row = wr * 64 + i * 16 + fr;
                const int cs = (kk * 32 + fkq * 8) ^ ((row & 7) * 8);
                a2[i] = *(const bf16x8*)(&kvs[row * 64 + cs]);
            }
#pragma unroll
            for (int j = 0; j < 8; j++) {
                const int row = 256 + wc * 128 + j * 16 + fr;
                const int cs = (kk * 32 + fkq * 8) ^ ((row & 7) * 8);
                b2v[j] = *(const bf16x8*)(&kvs[row * 64 + cs]);
            }
#pragma unroll
            for (int i = 0; i < 4; i++)
#pragma unroll
                for (int j = 0; j < 8; j++)
                    acc[i][j] = mfma16(a2[i], b2v[j], acc[i][j]);
        }
        __syncthreads();   // GEMM2 done reading kvs; next iter may overwrite
    }

    // epilogue: flush ctx tile + rsum partials
    float* cb = ctx + (size_t)b * C_ * C_;
#pragma unroll
    for (int i = 0; i < 4; i++) {
        const int gc = wr * 64 + i * 16 + fkq * 4;
#pragma unroll
        for (int j = 0; j < 8; j++) {
            const int gd = wc * 128 + j * 16 + fr;
#pragma unroll
            for (int r = 0; r < 4; r++)
                atomicAdd(&cb[(size_t)(gc + r) * C_ + gd], acc[i][j][r]);
        }
    }
#pragma unroll
    for (int i = 0; i < 2; i++)
#pragma unroll
        for (int r = 0; r < 4; r++) {
            float sv = rsacc[i][r];
            sv += __shfl_xor(sv, 1, 64);
            sv += __shfl_xor(sv, 2, 64);
            sv += __shfl_xor(sv, 4, 64);
            sv += __shfl_xor(sv, 8, 64);
            if (fr == 0)
                atomicAdd(&rsum[b * 256 + 32 * wave + i * 16 + fkq * 4 + r], sv);
        }
}

// ---------------------------------------------------------------------------
// K5a: T[b,o,c] = (sum_d Wp[o,d]*ctx[b,c,d]) / rsum[b,c]   (fp32 tiled)
// grid (4,4,8) : 64x64 tiles
// ---------------------------------------------------------------------------
__global__ __launch_bounds__(256) void k5a_T(const float* __restrict__ Wp,
                                             const float* __restrict__ ctx,
                                             const float* __restrict__ rsum,
                                             float* __restrict__ T) {
    __shared__ float Asm[64][65];
    __shared__ float Bsm[64][65];
    const int b = blockIdx.z;
    const int o0 = blockIdx.y * 64, c0 = blockIdx.x * 64;
    const int t = threadIdx.x;
    const int tm = t >> 4, tn = t & 15;
    const int lc4 = tn * 4;
    float acc[4][4] = {};
    const float* cb = ctx + (size_t)b * C_ * C_;
    for (int kk = 0; kk < 256; kk += 64) {
        __syncthreads();
#pragma unroll
        for (int p = 0; p < 4; p++) {
            const int r = p * 16 + tm;
            const float4 av = *(const float4*)(Wp + (size_t)(o0 + r) * C_ + kk + lc4);
            Asm[r][lc4] = av.x; Asm[r][lc4 + 1] = av.y; Asm[r][lc4 + 2] = av.z; Asm[r][lc4 + 3] = av.w;
            const float4 bv = *(const float4*)(cb + (size_t)(c0 + r) * C_ + kk + lc4);
            Bsm[r][lc4] = bv.x; Bsm[r][lc4 + 1] = bv.y; Bsm[r][lc4 + 2] = bv.z; Bsm[r][lc4 + 3] = bv.w;
        }
        __syncthreads();
        for (int k = 0; k < 64; k++) {
            float a_[4], b_[4];
#pragma unroll
            for (int i = 0; i < 4; i++) a_[i] = Asm[tm * 4 + i][k];
#pragma unroll
            for (int j = 0; j < 4; j++) b_[j] = Bsm[tn * 4 + j][k];
#pragma unroll
            for (int i = 0; i < 4; i++)
#pragma unroll
                for (int j = 0; j < 4; j++) acc[i][j] += a_[i] * b_[j];
        }
    }
    float isv[4];
#pragma unroll
    for (int j = 0; j < 4; j++) isv[j] = 1.f / rsum[b * 256 + c0 + tn * 4 + j];
#pragma unroll
    for (int i = 0; i < 4; i++)
#pragma unroll
        for (int j = 0; j < 4; j++)
            T[((size_t)b * C_ + o0 + tm * 4 + i) * C_ + c0 + tn * 4 + j] = acc[i][j] * isv[j];
}

// ---------------------------------------------------------------------------
// K5b: G[b,o,j] = inv[o] * sum_c T[b,o,c]*Wq[c,j]   -> bf16  (fp32 tiled)
// grid (4,4,8)
// ---------------------------------------------------------------------------
__global__ __launch_bounds__(256) void k5b_G(const float* __restrict__ Tm,
                                             const float* __restrict__ Wq,
                                             const float* __restrict__ inv,
                                             unsigned short* __restrict__ G) {
    __shared__ float Asm[64][65];   // T rows o, cols c (k)
    __shared__ float Bsm[64][65];   // Wq rows c (k), cols j
    const int b = blockIdx.z;
    const int o0 = blockIdx.y * 64, j0 = blockIdx.x * 64;
    const int t = threadIdx.x;
    const int tm = t >> 4, tn = t & 15;
    const int lc4 = tn * 4;
    float acc[4][4] = {};
    const float* Tb = Tm + (size_t)b * C_ * C_;
    for (int kk = 0; kk < 256; kk += 64) {
        __syncthreads();
#pragma unroll
        for (int p = 0; p < 4; p++) {
            const int r = p * 16 + tm;
            const float4 av = *(const float4*)(Tb + (size_t)(o0 + r) * C_ + kk + lc4);
            Asm[r][lc4] = av.x; Asm[r][lc4 + 1] = av.y; Asm[r][lc4 + 2] = av.z; Asm[r][lc4 + 3] = av.w;
            const float4 bv = *(const float4*)(Wq + (size_t)(kk + r) * C_ + j0 + lc4);
            Bsm[r][lc4] = bv.x; Bsm[r][lc4 + 1] = bv.y; Bsm[r][lc4 + 2] = bv.z; Bsm[r][lc4 + 3] = bv.w;
        }
        __syncthreads();
        for (int k = 0; k < 64; k++) {
            float a_[4], b_[4];
#pragma unroll
            for (int i = 0; i < 4; i++) a_[i] = Asm[tm * 4 + i][k];
#pragma unroll
            for (int j = 0; j < 4; j++) b_[j] = Bsm[k][tn * 4 + j];
#pragma unroll
            for (int i = 0; i < 4; i++)
#pragma unroll
                for (int j = 0; j < 4; j++) acc[i][j] += a_[i] * b_[j];
        }
    }
#pragma unroll
    for (int i = 0; i < 4; i++) {
        const float iv = inv[o0 + tm * 4 + i];
#pragma unroll
        for (int j = 0; j < 4; j++)
            G[((size_t)b * C_ + o0 + tm * 4 + i) * C_ + j0 + tn * 4 + j] = f2bf(acc[i][j] * iv);
    }
}

// ---------------------------------------------------------------------------
// K6: out[b,o,n] = relu( sum_j G[b,o,j]*xT[b,n,j] + b2[o] )  fp32 out
// grid (128 n-tiles, 2 m-tiles, 8)
// ---------------------------------------------------------------------------
__global__ __launch_bounds__(256) void k6_out(const unsigned short* __restrict__ G,
                                              const unsigned short* __restrict__ xT,
                                              const float* __restrict__ b2,
                                              float* __restrict__ out) {
    __shared__ __align__(16) unsigned short As[128 * 32];
    __shared__ __align__(16) unsigned short Bs[128 * 32];
    const int b  = blockIdx.z;
    const int m0 = blockIdx.y * 128;
    const int n0 = blockIdx.x * 128;
    const int t = threadIdx.x, wave = t >> 6, lane = t & 63;
    const int wm = wave >> 1, wn = wave & 1;

    const unsigned short* Gb  = G  + (size_t)b * C_ * C_;
    const unsigned short* xTb = xT + (size_t)b * N_ * C_;

    const int ch1 = wave * 64 + lane, ch2 = ch1 + 256;
    const int r1 = ch1 >> 2, q1 = ch1 & 3;
    const int r2 = ch2 >> 2, q2 = ch2 & 3;
    unsigned short* ldsA1 = As + wave * 512;
    unsigned short* ldsA2 = As + 2048 + wave * 512;
    unsigned short* ldsB1 = Bs + wave * 512;
    unsigned short* ldsB2 = Bs + 2048 + wave * 512;

    f32x4 acc[4][4];
#pragma unroll
    for (int i = 0; i < 4; i++)
#pragma unroll
        for (int j = 0; j < 4; j++)
#pragma unroll
            for (int r = 0; r < 4; r++) acc[i][j][r] = 0.f;

    const int fr = lane & 15;
    const int fk = (lane >> 4) * 8;

    for (int kk = 0; kk < 256; kk += 32) {
        __syncthreads();
        gl_lds16(Gb  + (size_t)(m0 + r1) * 256 + kk + q1 * 8, ldsA1);
        gl_lds16(Gb  + (size_t)(m0 + r2) * 256 + kk + q2 * 8, ldsA2);
        gl_lds16(xTb + (size_t)(n0 + r1) * 256 + kk + q1 * 8, ldsB1);
        gl_lds16(xTb + (size_t)(n0 + r2) * 256 + kk + q2 * 8, ldsB2);
        __syncthreads();
        bf16x8 af[4], bfv[4];
#pragma unroll
        for (int i = 0; i < 4; i++)
            af[i] = *(const bf16x8*)(As + (wm * 64 + i * 16 + fr) * 32 + fk);
#pragma unroll
        for (int j = 0; j < 4; j++)
            bfv[j] = *(const bf16x8*)(Bs + (wn * 64 + j * 16 + fr) * 32 + fk);
#pragma unroll
        for (int i = 0; i < 4; i++)
#pragma unroll
            for (int j = 0; j < 4; j++)
                acc[i][j] = mfma16(af[i], bfv[j], acc[i][j]);
    }

    const int col = lane & 15, rowq = (lane >> 4) * 4;
    float* ob = out + (size_t)b * C_ * N_;
#pragma unroll
    for (int i = 0; i < 4; i++) {
        const int gm = m0 + wm * 64 + i * 16 + rowq;
#pragma unroll
        for (int j = 0; j < 4; j++) {
            const int gn = n0 + wn * 64 + j * 16 + col;
#pragma unroll
            for (int r = 0; r < 4; r++) {
                const float val = fmaxf(acc[i][j][r] + b2[gm + r], 0.f);
                ob[(size_t)(gm + r) * N_ + gn] = val;
            }
        }
    }
}

// ---------------------------------------------------------------------------
extern "C" void kernel_launch(void* const* d_in, const int* in_sizes, int n_in,
                              void* d_out, int out_size, void* d_ws, size_t ws_size,
                              hipStream_t stream) {
    const float* x     = (const float*)d_in[0];
    const float* wqkv  = (const float*)d_in[1];
    const float* wproj = (const float*)d_in[2];
    const float* gamma = (const float*)d_in[3];
    const float* beta  = (const float*)d_in[4];
    const float* rmean = (const float*)d_in[5];
    const float* rvar  = (const float*)d_in[6];
    float* out = (float*)d_out;

    char* ws = (char*)d_ws;
    size_t off = 0;
    auto alloc = [&](size_t bytes) {
        void* p = ws + off;
        off += (bytes + 255) & ~(size_t)255;
        return p;
    };
    unsigned short* xT   = (unsigned short*)alloc((size_t)B_ * N_ * C_ * 2);  // 64 MiB
    unsigned short* WkvF = (unsigned short*)alloc((size_t)512 * 256 * 2);     // 256 KiB
    float* invp = (float*)alloc(256 * 4);
    float* b2p  = (float*)alloc(256 * 4);
    float* ctx  = (float*)alloc((size_t)B_ * C_ * C_ * 4);   // 2 MiB (mult. of 256)
    float* rsum = (float*)alloc(2048 * 4);                   // contiguous after ctx
    float* Tm   = (float*)alloc((size_t)B_ * C_ * C_ * 4);   // 2 MiB
    unsigned short* G = (unsigned short*)alloc((size_t)B_ * C_ * C_ * 2);

    hipLaunchKernelGGL(k1_transpose, dim3(256, 4, 8), dim3(256), 0, stream, x, xT);
    hipLaunchKernelGGL(k1b_setup, dim3(65), dim3(256), 0, stream,
                       wqkv, gamma, beta, rmean, rvar, WkvF, invp, b2p);
    // zero ctx + rsum in one fill (they are contiguous in the workspace)
    hipMemsetAsync(ctx, 0, (size_t)B_ * C_ * C_ * 4 + 2048 * 4, stream);
    hipLaunchKernelGGL(k2_ctx, dim3(32, 8), dim3(512), 0, stream, WkvF, xT, ctx, rsum);
    hipLaunchKernelGGL(k5a_T, dim3(4, 4, 8), dim3(256), 0, stream, wproj, ctx, rsum, Tm);
    hipLaunchKernelGGL(k5b_G, dim3(4, 4, 8), dim3(256), 0, stream, Tm, wqkv, invp, G);
    hipLaunchKernelGGL(k6_out, dim3(128, 2, 8), dim3(256), 0, stream, G, xT, b2p, out);
}

// Round 2
// 548.536 us; speedup vs baseline: 1.0622x; 1.0622x over previous
//
#include <hip/hip_runtime.h>
#include <stdint.h>

// Problem constants
#define B_   8
#define C_   256
#define N_   16384   // 128*128 spatial

typedef __attribute__((ext_vector_type(8))) short bf16x8;
typedef __attribute__((ext_vector_type(4))) float f32x4;

__device__ inline unsigned short f2bf(float f) {
    unsigned u = __float_as_uint(f);
    u += 0x7FFF + ((u >> 16) & 1);   // round-to-nearest-even
    return (unsigned short)(u >> 16);
}

// async global->LDS, 16B per lane. LDS dest = wave-uniform base + lane*16.
__device__ inline void gl_lds16(const void* g, void* l) {
    __builtin_amdgcn_global_load_lds(
        reinterpret_cast<const __attribute__((address_space(1))) unsigned int*>(
            reinterpret_cast<uintptr_t>(g)),
        reinterpret_cast<__attribute__((address_space(3))) unsigned int*>(
            reinterpret_cast<uintptr_t>(l)),
        16, 0, 0);
}

__device__ inline f32x4 mfma16(bf16x8 a, bf16x8 b, f32x4 c) {
    return __builtin_amdgcn_mfma_f32_16x16x32_bf16(a, b, c, 0, 0, 0);
}

// ---------------------------------------------------------------------------
// K1: x [B,C,N] fp32  ->  xT [B,N,C] bf16   (64x64 tiles through LDS)
// ---------------------------------------------------------------------------
__global__ __launch_bounds__(256) void k1_transpose(const float* __restrict__ x,
                                                    unsigned short* __restrict__ xT) {
    __shared__ unsigned short tile[64][65];
    const int b = blockIdx.z, c0 = blockIdx.y * 64, n0 = blockIdx.x * 64;
    const float* xb = x + (size_t)b * C_ * N_;
    const int t = threadIdx.x;
    const int tr = t >> 4, tc4 = (t & 15) * 4;
#pragma unroll
    for (int p = 0; p < 4; p++) {
        const int i = p * 16 + tr;   // c index
        const float4 v = *(const float4*)(xb + (size_t)(c0 + i) * N_ + n0 + tc4);
        tile[i][tc4 + 0] = f2bf(v.x);
        tile[i][tc4 + 1] = f2bf(v.y);
        tile[i][tc4 + 2] = f2bf(v.z);
        tile[i][tc4 + 3] = f2bf(v.w);
    }
    __syncthreads();
    unsigned short* xTb = xT + (size_t)b * N_ * C_;
#pragma unroll
    for (int p = 0; p < 4; p++) {
        const int jj = p * 16 + tr;  // n index
        ushort4 o;
        o.x = tile[tc4 + 0][jj];
        o.y = tile[tc4 + 1][jj];
        o.z = tile[tc4 + 2][jj];
        o.w = tile[tc4 + 3][jj];
        *(ushort4*)(xTb + (size_t)(n0 + jj) * C_ + c0 + tc4) = o;
    }
}

// ---------------------------------------------------------------------------
// K1b: blocks 0..63: pack w_kv (wqkv rows 256..767) into fragment-major bf16:
//      WkvF[((rowblk*8 + kblk)*64 + lane)*8 + e] = wkv[rowblk*16 + (lane&15),
//                                                      kblk*32 + (lane>>4)*8 + e]
//      block 64: BN constants.
// ---------------------------------------------------------------------------
__global__ __launch_bounds__(256) void k1b_setup(const float* __restrict__ wqkv,
                                                 const float* __restrict__ gamma,
                                                 const float* __restrict__ beta,
                                                 const float* __restrict__ rmean,
                                                 const float* __restrict__ rvar,
                                                 unsigned short* __restrict__ WkvF,
                                                 float* __restrict__ inv,
                                                 float* __restrict__ b2) {
    const int t = threadIdx.x;
    if (blockIdx.x < 64) {
        const int chunk = blockIdx.x * 256 + t;   // 16384 chunks of 8 shorts
        const int lane = chunk & 63;
        const int kb = (chunk >> 6) & 7;
        const int rb = chunk >> 9;                // 0..31
        const int row = rb * 16 + (lane & 15);    // 0..511 (kv row)
        const int k0 = kb * 32 + (lane >> 4) * 8;
        const float* src = wqkv + (size_t)(256 + row) * 256 + k0;
        const float4 a = *(const float4*)(src);
        const float4 c = *(const float4*)(src + 4);
        ushort4 o0, o1;
        o0.x = f2bf(a.x); o0.y = f2bf(a.y); o0.z = f2bf(a.z); o0.w = f2bf(a.w);
        o1.x = f2bf(c.x); o1.y = f2bf(c.y); o1.z = f2bf(c.z); o1.w = f2bf(c.w);
        *(ushort4*)(WkvF + (size_t)chunk * 8) = o0;
        *(ushort4*)(WkvF + (size_t)chunk * 8 + 4) = o1;
    } else {
        const float iv = gamma[t] * rsqrtf(rvar[t] + 1e-5f);
        inv[t] = iv;
        b2[t]  = beta[t] - rmean[t] * iv;
    }
}

// ---------------------------------------------------------------------------
// K2: FUSED kv-GEMM + exp + context GEMM, d-SPLIT to keep registers small.
//  Block = (n-chunk of 1024, d-half h, batch b). 16 subchunks of 64 n:
//    stage xT[64n,256c] -> LDS (double-buffered, src-swizzled),
//    kv rows: all 256 k rows + this block's 128 v rows,
//    exp() on k part (+rsum partials, h==0 only),
//    kv -> swizzled LDS,  ctx[256c,128d] += expk @ v^T (acc[4][4] = 64 VGPR).
//  Epilogue: plain store of ctx partial (per n-chunk); reduced by k4r.
//  grid (16, 2, 8), 512 threads. LDS = 112 KiB.
// ---------------------------------------------------------------------------
__global__ __launch_bounds__(512, 2) void k2_ctx(const unsigned short* __restrict__ WkvF,
                                                 const unsigned short* __restrict__ xT,
                                                 float* __restrict__ cp,
                                                 float* __restrict__ rsum) {
    __shared__ __align__(16) unsigned short xs[2][64 * 256];   // 2 x 32 KiB
    __shared__ __align__(16) unsigned short kvs[384 * 64];     // 48 KiB
    const int chunk = blockIdx.x;
    const int h  = blockIdx.y;
    const int b  = blockIdx.z;
    const int n0 = chunk * 1024;
    const int t = threadIdx.x, wave = t >> 6, lane = t & 63;
    const int fr = lane & 15, fkq = lane >> 4;                 // frag row / k-quad
    const int wr = wave >> 1, wc = wave & 1;                   // ctx wave grid 4x2
    const unsigned short* xTb = xT + (size_t)b * N_ * C_;

    // this wave's three kv rowblocks (16 rows each):
    //   slot0: rowblk wave        (k), slot1: rowblk 8+wave (k),
    //   slot2: global rowblk 16 + h*8 + wave (v half)
    const int rbv = 16 + h * 8 + wave;

    f32x4 acc[4][4];                 // ctx tile 64c x 64d per wave
#pragma unroll
    for (int i = 0; i < 4; i++)
#pragma unroll
        for (int j = 0; j < 4; j++)
#pragma unroll
            for (int r = 0; r < 4; r++) acc[i][j][r] = 0.f;
    float rsacc[2][4];               // row-sum partials (k slots)
#pragma unroll
    for (int i = 0; i < 2; i++)
#pragma unroll
        for (int r = 0; r < 4; r++) rsacc[i][r] = 0.f;

    // stage subchunk sc (64 n-rows x 256 c) into xs[buf]; LDS linear,
    // global source columns inverse-swizzled: xs[r*256+c] = xT[nb+r][c ^ ((r&7)*8)]
    auto stage = [&](int buf, int sc) {
        const int nb = n0 + sc * 64;
#pragma unroll
        for (int it = 0; it < 4; it++) {
            const int idx = it * 512 + t;        // 16B-chunk id, 0..2047
            const int r = idx >> 5;              // n row 0..63
            const int c = (idx & 31) * 8;        // c col (short units)
            const int csw = c ^ ((r & 7) * 8);
            gl_lds16(xTb + (size_t)(nb + r) * 256 + csw,
                     &xs[buf][it * 4096 + wave * 512]);
        }
    };

    stage(0, 0);
    __syncthreads();

    for (int s = 0; s < 16; ++s) {
        const int cur = s & 1;
        if (s < 15) stage(cur ^ 1, s + 1);       // prefetch next subchunk

        // GEMM1: 3 rowblocks x 64n per wave, K=256
        f32x4 kacc[3][4];
#pragma unroll
        for (int i = 0; i < 3; i++)
#pragma unroll
            for (int j = 0; j < 4; j++)
#pragma unroll
                for (int r = 0; r < 4; r++) kacc[i][j][r] = 0.f;
#pragma unroll
        for (int kb = 0; kb < 8; kb++) {
            bf16x8 bfv[4];
#pragma unroll
            for (int j = 0; j < 4; j++) {
                const int rr = j * 16 + fr;
                const int cs = (kb * 32 + fkq * 8) ^ ((rr & 7) * 8);
                bfv[j] = *(const bf16x8*)(&xs[cur][rr * 256 + cs]);
            }
            const bf16x8 a0 = *(const bf16x8*)(
                WkvF + (((size_t)(wave)      * 8 + kb) * 64 + lane) * 8);
            const bf16x8 a1 = *(const bf16x8*)(
                WkvF + (((size_t)(8 + wave)  * 8 + kb) * 64 + lane) * 8);
            const bf16x8 a2v = *(const bf16x8*)(
                WkvF + (((size_t)rbv         * 8 + kb) * 64 + lane) * 8);
#pragma unroll
            for (int j = 0; j < 4; j++) kacc[0][j] = mfma16(a0,  bfv[j], kacc[0][j]);
#pragma unroll
            for (int j = 0; j < 4; j++) kacc[1][j] = mfma16(a1,  bfv[j], kacc[1][j]);
#pragma unroll
            for (int j = 0; j < 4; j++) kacc[2][j] = mfma16(a2v, bfv[j], kacc[2][j]);
            if (kb & 1) __builtin_amdgcn_sched_barrier(0);  // cap load hoisting
        }
        // exp (k slots) + write to swizzled kvs
#pragma unroll
        for (int slot = 0; slot < 3; slot++) {
            const int rowb = (slot * 8 + wave) * 16 + fkq * 4;
#pragma unroll
            for (int j = 0; j < 4; j++) {
                const int cn = j * 16 + fr;
#pragma unroll
                for (int r = 0; r < 4; r++) {
                    float vv = kacc[slot][j][r];
                    if (slot < 2) { vv = __expf(vv); rsacc[slot][r] += vv; }
                    const int row = rowb + r;
                    kvs[row * 64 + (cn ^ ((row & 7) * 8))] = f2bf(vv);
                }
            }
        }
        __syncthreads();   // kvs complete (also drains prefetch vmcnt)

        // GEMM2: ctx[64c x 64d] += expk[64c x 64n] * v[64d x 64n]^T
#pragma unroll
        for (int kk = 0; kk < 2; kk++) {
            bf16x8 a2[4], b2v[4];
#pragma unroll
            for (int i = 0; i < 4; i++) {
                const int row = wr * 64 + i * 16 + fr;
                const int cs = (kk * 32 + fkq * 8) ^ ((row & 7) * 8);
                a2[i] = *(const bf16x8*)(&kvs[row * 64 + cs]);
            }
#pragma unroll
            for (int j = 0; j < 4; j++) {
                const int row = 256 + wc * 64 + j * 16 + fr;
                const int cs = (kk * 32 + fkq * 8) ^ ((row & 7) * 8);
                b2v[j] = *(const bf16x8*)(&kvs[row * 64 + cs]);
            }
#pragma unroll
            for (int i = 0; i < 4; i++)
#pragma unroll
                for (int j = 0; j < 4; j++)
                    acc[i][j] = mfma16(a2[i], b2v[j], acc[i][j]);
        }
        __syncthreads();   // GEMM2 done reading kvs; next iter may overwrite
    }

    // epilogue: plain store of ctx partial tile [256c x 128d]
    float* cpb = cp + ((size_t)((b * 2 + h) * 16 + chunk)) * 256 * 128;
#pragma unroll
    for (int i = 0; i < 4; i++) {
        const int gc = wr * 64 + i * 16 + fkq * 4;
#pragma unroll
        for (int j = 0; j < 4; j++) {
            const int gd = wc * 64 + j * 16 + fr;
#pragma unroll
            for (int r = 0; r < 4; r++)
                cpb[(size_t)(gc + r) * 128 + gd] = acc[i][j][r];
        }
    }
    // rsum partials (only the h==0 half contributes, else doubled)
    if (h == 0) {
#pragma unroll
        for (int slot = 0; slot < 2; slot++)
#pragma unroll
            for (int r = 0; r < 4; r++) {
                float sv = rsacc[slot][r];
                sv += __shfl_xor(sv, 1, 64);
                sv += __shfl_xor(sv, 2, 64);
                sv += __shfl_xor(sv, 4, 64);
                sv += __shfl_xor(sv, 8, 64);
                if (fr == 0)
                    atomicAdd(&rsum[b * 256 + (slot * 8 + wave) * 16 + fkq * 4 + r], sv);
            }
    }
}

// ---------------------------------------------------------------------------
// K4r: ctx[b][c][h*128+d] = sum over 16 n-chunk partials of cp.
// grid 512 x 256 threads, one float4 per thread.
// ---------------------------------------------------------------------------
__global__ __launch_bounds__(256) void k4r_reduce(const float* __restrict__ cp,
                                                  float* __restrict__ ctx) {
    const int gid = blockIdx.x * 256 + threadIdx.x;   // 0..131071
    const int d4 = gid & 31;
    const int c  = (gid >> 5) & 255;
    const int h  = (gid >> 13) & 1;
    const int b  = gid >> 14;
    const float* src = cp + ((size_t)((b * 2 + h) * 16) * 256 + c) * 128 + d4 * 4;
    f32x4 s = {0.f, 0.f, 0.f, 0.f};
#pragma unroll
    for (int k = 0; k < 16; k++)
        s = s + *(const f32x4*)(src + (size_t)k * 32768);
    *(f32x4*)(ctx + ((size_t)b * 256 + c) * 256 + h * 128 + d4 * 4) = s;
}

// ---------------------------------------------------------------------------
// K5a: T[b,o,c] = (sum_d Wp[o,d]*ctx[b,c,d]) / rsum[b,c]   (fp32 tiled)
// grid (4,4,8) : 64x64 tiles
// ---------------------------------------------------------------------------
__global__ __launch_bounds__(256) void k5a_T(const float* __restrict__ Wp,
                                             const float* __restrict__ ctx,
                                             const float* __restrict__ rsum,
                                             float* __restrict__ T) {
    __shared__ float Asm[64][65];
    __shared__ float Bsm[64][65];
    const int b = blockIdx.z;
    const int o0 = blockIdx.y * 64, c0 = blockIdx.x * 64;
    const int t = threadIdx.x;
    const int tm = t >> 4, tn = t & 15;
    const int lc4 = tn * 4;
    float acc[4][4] = {};
    const float* cb = ctx + (size_t)b * C_ * C_;
    for (int kk = 0; kk < 256; kk += 64) {
        __syncthreads();
#pragma unroll
        for (int p = 0; p < 4; p++) {
            const int r = p * 16 + tm;
            const float4 av = *(const float4*)(Wp + (size_t)(o0 + r) * C_ + kk + lc4);
            Asm[r][lc4] = av.x; Asm[r][lc4 + 1] = av.y; Asm[r][lc4 + 2] = av.z; Asm[r][lc4 + 3] = av.w;
            const float4 bv = *(const float4*)(cb + (size_t)(c0 + r) * C_ + kk + lc4);
            Bsm[r][lc4] = bv.x; Bsm[r][lc4 + 1] = bv.y; Bsm[r][lc4 + 2] = bv.z; Bsm[r][lc4 + 3] = bv.w;
        }
        __syncthreads();
        for (int k = 0; k < 64; k++) {
            float a_[4], b_[4];
#pragma unroll
            for (int i = 0; i < 4; i++) a_[i] = Asm[tm * 4 + i][k];
#pragma unroll
            for (int j = 0; j < 4; j++) b_[j] = Bsm[tn * 4 + j][k];
#pragma unroll
            for (int i = 0; i < 4; i++)
#pragma unroll
                for (int j = 0; j < 4; j++) acc[i][j] += a_[i] * b_[j];
        }
    }
    float isv[4];
#pragma unroll
    for (int j = 0; j < 4; j++) isv[j] = 1.f / rsum[b * 256 + c0 + tn * 4 + j];
#pragma unroll
    for (int i = 0; i < 4; i++)
#pragma unroll
        for (int j = 0; j < 4; j++)
            T[((size_t)b * C_ + o0 + tm * 4 + i) * C_ + c0 + tn * 4 + j] = acc[i][j] * isv[j];
}

// ---------------------------------------------------------------------------
// K5b: G[b,o,j] = inv[o] * sum_c T[b,o,c]*Wq[c,j]   -> bf16  (fp32 tiled)
// grid (4,4,8)
// ---------------------------------------------------------------------------
__global__ __launch_bounds__(256) void k5b_G(const float* __restrict__ Tm,
                                             const float* __restrict__ Wq,
                                             const float* __restrict__ inv,
                                             unsigned short* __restrict__ G) {
    __shared__ float Asm[64][65];   // T rows o, cols c (k)
    __shared__ float Bsm[64][65];   // Wq rows c (k), cols j
    const int b = blockIdx.z;
    const int o0 = blockIdx.y * 64, j0 = blockIdx.x * 64;
    const int t = threadIdx.x;
    const int tm = t >> 4, tn = t & 15;
    const int lc4 = tn * 4;
    float acc[4][4] = {};
    const float* Tb = Tm + (size_t)b * C_ * C_;
    for (int kk = 0; kk < 256; kk += 64) {
        __syncthreads();
#pragma unroll
        for (int p = 0; p < 4; p++) {
            const int r = p * 16 + tm;
            const float4 av = *(const float4*)(Tb + (size_t)(o0 + r) * C_ + kk + lc4);
            Asm[r][lc4] = av.x; Asm[r][lc4 + 1] = av.y; Asm[r][lc4 + 2] = av.z; Asm[r][lc4 + 3] = av.w;
            const float4 bv = *(const float4*)(Wq + (size_t)(kk + r) * C_ + j0 + lc4);
            Bsm[r][lc4] = bv.x; Bsm[r][lc4 + 1] = bv.y; Bsm[r][lc4 + 2] = bv.z; Bsm[r][lc4 + 3] = bv.w;
        }
        __syncthreads();
        for (int k = 0; k < 64; k++) {
            float a_[4], b_[4];
#pragma unroll
            for (int i = 0; i < 4; i++) a_[i] = Asm[tm * 4 + i][k];
#pragma unroll
            for (int j = 0; j < 4; j++) b_[j] = Bsm[k][tn * 4 + j];
#pragma unroll
            for (int i = 0; i < 4; i++)
#pragma unroll
                for (int j = 0; j < 4; j++) acc[i][j] += a_[i] * b_[j];
        }
    }
#pragma unroll
    for (int i = 0; i < 4; i++) {
        const float iv = inv[o0 + tm * 4 + i];
#pragma unroll
        for (int j = 0; j < 4; j++)
            G[((size_t)b * C_ + o0 + tm * 4 + i) * C_ + j0 + tn * 4 + j] = f2bf(acc[i][j] * iv);
    }
}

// ---------------------------------------------------------------------------
// K6: out[b,o,n] = relu( sum_j G[b,o,j]*xT[b,n,j] + b2[o] )  fp32 out
// grid (128 n-tiles, 2 m-tiles, 8)
// ---------------------------------------------------------------------------
__global__ __launch_bounds__(256) void k6_out(const unsigned short* __restrict__ G,
                                              const unsigned short* __restrict__ xT,
                                              const float* __restrict__ b2,
                                              float* __restrict__ out) {
    __shared__ __align__(16) unsigned short As[128 * 32];
    __shared__ __align__(16) unsigned short Bs[128 * 32];
    const int b  = blockIdx.z;
    const int m0 = blockIdx.y * 128;
    const int n0 = blockIdx.x * 128;
    const int t = threadIdx.x, wave = t >> 6, lane = t & 63;
    const int wm = wave >> 1, wn = wave & 1;

    const unsigned short* Gb  = G  + (size_t)b * C_ * C_;
    const unsigned short* xTb = xT + (size_t)b * N_ * C_;

    const int ch1 = wave * 64 + lane, ch2 = ch1 + 256;
    const int r1 = ch1 >> 2, q1 = ch1 & 3;
    const int r2 = ch2 >> 2, q2 = ch2 & 3;
    unsigned short* ldsA1 = As + wave * 512;
    unsigned short* ldsA2 = As + 2048 + wave * 512;
    unsigned short* ldsB1 = Bs + wave * 512;
    unsigned short* ldsB2 = Bs + 2048 + wave * 512;

    f32x4 acc[4][4];
#pragma unroll
    for (int i = 0; i < 4; i++)
#pragma unroll
        for (int j = 0; j < 4; j++)
#pragma unroll
            for (int r = 0; r < 4; r++) acc[i][j][r] = 0.f;

    const int fr = lane & 15;
    const int fk = (lane >> 4) * 8;

    for (int kk = 0; kk < 256; kk += 32) {
        __syncthreads();
        gl_lds16(Gb  + (size_t)(m0 + r1) * 256 + kk + q1 * 8, ldsA1);
        gl_lds16(Gb  + (size_t)(m0 + r2) * 256 + kk + q2 * 8, ldsA2);
        gl_lds16(xTb + (size_t)(n0 + r1) * 256 + kk + q1 * 8, ldsB1);
        gl_lds16(xTb + (size_t)(n0 + r2) * 256 + kk + q2 * 8, ldsB2);
        __syncthreads();
        bf16x8 af[4], bfv[4];
#pragma unroll
        for (int i = 0; i < 4; i++)
            af[i] = *(const bf16x8*)(As + (wm * 64 + i * 16 + fr) * 32 + fk);
#pragma unroll
        for (int j = 0; j < 4; j++)
            bfv[j] = *(const bf16x8*)(Bs + (wn * 64 + j * 16 + fr) * 32 + fk);
#pragma unroll
        for (int i = 0; i < 4; i++)
#pragma unroll
            for (int j = 0; j < 4; j++)
                acc[i][j] = mfma16(af[i], bfv[j], acc[i][j]);
    }

    const int col = lane & 15, rowq = (lane >> 4) * 4;
    float* ob = out + (size_t)b * C_ * N_;
#pragma unroll
    for (int i = 0; i < 4; i++) {
        const int gm = m0 + wm * 64 + i * 16 + rowq;
#pragma unroll
        for (int j = 0; j < 4; j++) {
            const int gn = n0 + wn * 64 + j * 16 + col;
#pragma unroll
            for (int r = 0; r < 4; r++) {
                const float val = fmaxf(acc[i][j][r] + b2[gm + r], 0.f);
                ob[(size_t)(gm + r) * N_ + gn] = val;
            }
        }
    }
}

// ---------------------------------------------------------------------------
extern "C" void kernel_launch(void* const* d_in, const int* in_sizes, int n_in,
                              void* d_out, int out_size, void* d_ws, size_t ws_size,
                              hipStream_t stream) {
    const float* x     = (const float*)d_in[0];
    const float* wqkv  = (const float*)d_in[1];
    const float* wproj = (const float*)d_in[2];
    const float* gamma = (const float*)d_in[3];
    const float* beta  = (const float*)d_in[4];
    const float* rmean = (const float*)d_in[5];
    const float* rvar  = (const float*)d_in[6];
    float* out = (float*)d_out;

    char* ws = (char*)d_ws;
    size_t off = 0;
    auto alloc = [&](size_t bytes) {
        void* p = ws + off;
        off += (bytes + 255) & ~(size_t)255;
        return p;
    };
    unsigned short* xT   = (unsigned short*)alloc((size_t)B_ * N_ * C_ * 2);  // 64 MiB
    unsigned short* WkvF = (unsigned short*)alloc((size_t)512 * 256 * 2);     // 256 KiB
    float* invp = (float*)alloc(256 * 4);
    float* b2p  = (float*)alloc(256 * 4);
    float* cp   = (float*)alloc((size_t)256 * 256 * 128 * 4);  // 32 MiB partials
    float* ctx  = (float*)alloc((size_t)B_ * C_ * C_ * 4);     // 2 MiB
    float* rsum = (float*)alloc(2048 * 4);
    float* Tm   = (float*)alloc((size_t)B_ * C_ * C_ * 4);     // 2 MiB
    unsigned short* G = (unsigned short*)alloc((size_t)B_ * C_ * C_ * 2);

    hipLaunchKernelGGL(k1_transpose, dim3(256, 4, 8), dim3(256), 0, stream, x, xT);
    hipLaunchKernelGGL(k1b_setup, dim3(65), dim3(256), 0, stream,
                       wqkv, gamma, beta, rmean, rvar, WkvF, invp, b2p);
    hipMemsetAsync(rsum, 0, 2048 * 4, stream);
    hipLaunchKernelGGL(k2_ctx, dim3(16, 2, 8), dim3(512), 0, stream, WkvF, xT, cp, rsum);
    hipLaunchKernelGGL(k4r_reduce, dim3(512), dim3(256), 0, stream, cp, ctx);
    hipLaunchKernelGGL(k5a_T, dim3(4, 4, 8), dim3(256), 0, stream, wproj, ctx, rsum, Tm);
    hipLaunchKernelGGL(k5b_G, dim3(4, 4, 8), dim3(256), 0, stream, Tm, wqkv, invp, G);
    hipLaunchKernelGGL(k6_out, dim3(128, 2, 8), dim3(256), 0, stream, G, xT, b2p, out);
}

// Round 3
// 384.281 us; speedup vs baseline: 1.5162x; 1.4274x over previous
//
#include <hip/hip_runtime.h>
#include <stdint.h>

// Problem constants
#define B_   8
#define C_   256
#define N_   16384   // 128*128 spatial

typedef __attribute__((ext_vector_type(8))) short bf16x8;
typedef __attribute__((ext_vector_type(4))) float f32x4;

__device__ inline unsigned short f2bf(float f) {
    unsigned u = __float_as_uint(f);
    u += 0x7FFF + ((u >> 16) & 1);   // round-to-nearest-even
    return (unsigned short)(u >> 16);
}

// async global->LDS, 16B per lane. LDS dest = wave-uniform base + lane*16.
__device__ inline void gl_lds16(const void* g, void* l) {
    __builtin_amdgcn_global_load_lds(
        reinterpret_cast<const __attribute__((address_space(1))) unsigned int*>(
            reinterpret_cast<uintptr_t>(g)),
        reinterpret_cast<__attribute__((address_space(3))) unsigned int*>(
            reinterpret_cast<uintptr_t>(l)),
        16, 0, 0);
}

__device__ inline f32x4 mfma16(bf16x8 a, bf16x8 b, f32x4 c) {
    return __builtin_amdgcn_mfma_f32_16x16x32_bf16(a, b, c, 0, 0, 0);
}

// ---------------------------------------------------------------------------
// K1: x [B,C,N] fp32  ->  xT [B,N,C] bf16   (64x64 tiles through LDS)
// ---------------------------------------------------------------------------
__global__ __launch_bounds__(256) void k1_transpose(const float* __restrict__ x,
                                                    unsigned short* __restrict__ xT) {
    __shared__ unsigned short tile[64][65];
    const int b = blockIdx.z, c0 = blockIdx.y * 64, n0 = blockIdx.x * 64;
    const float* xb = x + (size_t)b * C_ * N_;
    const int t = threadIdx.x;
    const int tr = t >> 4, tc4 = (t & 15) * 4;
#pragma unroll
    for (int p = 0; p < 4; p++) {
        const int i = p * 16 + tr;   // c index
        const float4 v = *(const float4*)(xb + (size_t)(c0 + i) * N_ + n0 + tc4);
        tile[i][tc4 + 0] = f2bf(v.x);
        tile[i][tc4 + 1] = f2bf(v.y);
        tile[i][tc4 + 2] = f2bf(v.z);
        tile[i][tc4 + 3] = f2bf(v.w);
    }
    __syncthreads();
    unsigned short* xTb = xT + (size_t)b * N_ * C_;
#pragma unroll
    for (int p = 0; p < 4; p++) {
        const int jj = p * 16 + tr;  // n index
        ushort4 o;
        o.x = tile[tc4 + 0][jj];
        o.y = tile[tc4 + 1][jj];
        o.z = tile[tc4 + 2][jj];
        o.w = tile[tc4 + 3][jj];
        *(ushort4*)(xTb + (size_t)(n0 + jj) * C_ + c0 + tc4) = o;
    }
}

// ---------------------------------------------------------------------------
// K1b: blocks 0..63: pack w_kv (wqkv rows 256..767) into fragment-major bf16:
//      WkvF[((rowblk*8 + kblk)*64 + lane)*8 + e] = wkv[rowblk*16 + (lane&15),
//                                                      kblk*32 + (lane>>4)*8 + e]
//      block 64: BN constants.
// ---------------------------------------------------------------------------
__global__ __launch_bounds__(256) void k1b_setup(const float* __restrict__ wqkv,
                                                 const float* __restrict__ gamma,
                                                 const float* __restrict__ beta,
                                                 const float* __restrict__ rmean,
                                                 const float* __restrict__ rvar,
                                                 unsigned short* __restrict__ WkvF,
                                                 float* __restrict__ inv,
                                                 float* __restrict__ b2) {
    const int t = threadIdx.x;
    if (blockIdx.x < 64) {
        const int chunk = blockIdx.x * 256 + t;   // 16384 chunks of 8 shorts
        const int lane = chunk & 63;
        const int kb = (chunk >> 6) & 7;
        const int rb = chunk >> 9;                // 0..31
        const int row = rb * 16 + (lane & 15);    // 0..511 (kv row)
        const int k0 = kb * 32 + (lane >> 4) * 8;
        const float* src = wqkv + (size_t)(256 + row) * 256 + k0;
        const float4 a = *(const float4*)(src);
        const float4 c = *(const float4*)(src + 4);
        ushort4 o0, o1;
        o0.x = f2bf(a.x); o0.y = f2bf(a.y); o0.z = f2bf(a.z); o0.w = f2bf(a.w);
        o1.x = f2bf(c.x); o1.y = f2bf(c.y); o1.z = f2bf(c.z); o1.w = f2bf(c.w);
        *(ushort4*)(WkvF + (size_t)chunk * 8) = o0;
        *(ushort4*)(WkvF + (size_t)chunk * 8 + 4) = o1;
    } else {
        const float iv = gamma[t] * rsqrtf(rvar[t] + 1e-5f);
        inv[t] = iv;
        b2[t]  = beta[t] - rmean[t] * iv;
    }
}

// ---------------------------------------------------------------------------
// K2: FUSED kv-GEMM + exp + context GEMM, d-split, W held in registers.
//  Block = (n-chunk of 1024, d-half h, batch b). 16 subchunks of 64 n:
//    stage xT[64n,256c] -> LDS (double-buffered, src-swizzled),
//    GEMM1 in 2 sequential n-phases (kacc[3][2] only; W frags persistent in
//    VGPRs so the inner loop has ZERO global loads),
//    exp() on k rows (+rsum partials), kv -> swizzled LDS,
//    GEMM2: ctx[256c,128d] += expk @ v^T (acc[4][4]/wave in AGPRs).
//  Epilogue: plain store of ctx partial (per n-chunk); reduced by k4r.
//  grid (16, 2, 8), 512 threads. LDS = 112 KiB.
// ---------------------------------------------------------------------------
__global__ __launch_bounds__(512, 2) void k2_ctx(const unsigned short* __restrict__ WkvF,
                                                 const unsigned short* __restrict__ xT,
                                                 float* __restrict__ cp,
                                                 float* __restrict__ rsum) {
    __shared__ __align__(16) unsigned short xs[2][64 * 256];   // 2 x 32 KiB
    __shared__ __align__(16) unsigned short kvs[384 * 64];     // 48 KiB
    const int chunk = blockIdx.x;
    const int h  = blockIdx.y;
    const int b  = blockIdx.z;
    const int n0 = chunk * 1024;
    const int t = threadIdx.x, wave = t >> 6, lane = t & 63;
    const int fr = lane & 15, fkq = lane >> 4;                 // frag row / k-quad
    const int wr = wave >> 1, wc = wave & 1;                   // ctx wave grid 4x2
    const unsigned short* xTb = xT + (size_t)b * N_ * C_;

    // persistent W fragments: 3 rowblocks x 8 kb = 24 x bf16x8 (96 VGPR).
    //   slot0: k rowblk wave, slot1: k rowblk 8+wave, slot2: v rowblk 16+h*8+wave
    bf16x8 wf[3][8];
    {
        const int rbs[3] = {wave, 8 + wave, 16 + h * 8 + wave};
#pragma unroll
        for (int slot = 0; slot < 3; slot++)
#pragma unroll
            for (int kb = 0; kb < 8; kb++)
                wf[slot][kb] = *(const bf16x8*)(
                    WkvF + (((size_t)rbs[slot] * 8 + kb) * 64 + lane) * 8);
    }

    f32x4 acc[4][4];                 // ctx tile 64c x 64d per wave
#pragma unroll
    for (int i = 0; i < 4; i++)
#pragma unroll
        for (int j = 0; j < 4; j++)
#pragma unroll
            for (int r = 0; r < 4; r++) acc[i][j][r] = 0.f;
    float rsacc[2][4];               // row-sum partials (k slots)
#pragma unroll
    for (int i = 0; i < 2; i++)
#pragma unroll
        for (int r = 0; r < 4; r++) rsacc[i][r] = 0.f;

    // stage subchunk sc (64 n-rows x 256 c) into xs[buf]; LDS linear,
    // global source columns inverse-swizzled: xs[r*256+c] = xT[nb+r][c ^ ((r&7)*8)]
    auto stage = [&](int buf, int sc) {
        const int nb = n0 + sc * 64;
#pragma unroll
        for (int it = 0; it < 4; it++) {
            const int idx = it * 512 + t;        // 16B-chunk id, 0..2047
            const int r = idx >> 5;              // n row 0..63
            const int c = (idx & 31) * 8;        // c col (short units)
            const int csw = c ^ ((r & 7) * 8);
            gl_lds16(xTb + (size_t)(nb + r) * 256 + csw,
                     &xs[buf][it * 4096 + wave * 512]);
        }
    };

    stage(0, 0);
    __syncthreads();

    for (int s = 0; s < 16; ++s) {
        const int cur = s & 1;
        if (s < 15) stage(cur ^ 1, s + 1);       // prefetch next subchunk

        // GEMM1: two sequential phases over n (NOT unrolled: bounds register
        // pressure; kacc[3][2]=24 regs, dead after each phase's exp/write)
#pragma unroll 1
        for (int p = 0; p < 2; ++p) {
            f32x4 kacc[3][2];
#pragma unroll
            for (int i = 0; i < 3; i++)
#pragma unroll
                for (int j = 0; j < 2; j++)
#pragma unroll
                    for (int r = 0; r < 4; r++) kacc[i][j][r] = 0.f;
#pragma unroll
            for (int kb = 0; kb < 8; kb++) {
                bf16x8 bfv[2];
#pragma unroll
                for (int jj = 0; jj < 2; jj++) {
                    const int rr = (p * 2 + jj) * 16 + fr;
                    const int cs = (kb * 32 + fkq * 8) ^ ((fr & 7) * 8);
                    bfv[jj] = *(const bf16x8*)(&xs[cur][rr * 256 + cs]);
                }
#pragma unroll
                for (int slot = 0; slot < 3; slot++) {
                    kacc[slot][0] = mfma16(wf[slot][kb], bfv[0], kacc[slot][0]);
                    kacc[slot][1] = mfma16(wf[slot][kb], bfv[1], kacc[slot][1]);
                }
            }
            // exp (k slots) + write to swizzled kvs
#pragma unroll
            for (int slot = 0; slot < 3; slot++) {
                const int rowb = (slot * 8 + wave) * 16 + fkq * 4;
#pragma unroll
                for (int jj = 0; jj < 2; jj++) {
                    const int cn = (p * 2 + jj) * 16 + fr;
#pragma unroll
                    for (int r = 0; r < 4; r++) {
                        float vv = kacc[slot][jj][r];
                        if (slot < 2) { vv = __expf(vv); rsacc[slot][r] += vv; }
                        const int row = rowb + r;
                        kvs[row * 64 + (cn ^ ((row & 7) * 8))] = f2bf(vv);
                    }
                }
            }
        }
        __syncthreads();   // kvs complete (also drains prefetch vmcnt)

        // GEMM2: ctx[64c x 64d] += expk[64c x 64n] * v[64d x 64n]^T
#pragma unroll
        for (int kk = 0; kk < 2; kk++) {
            bf16x8 a2[4], b2v[4];
#pragma unroll
            for (int i = 0; i < 4; i++) {
                const int row = wr * 64 + i * 16 + fr;
                const int cs = (kk * 32 + fkq * 8) ^ ((row & 7) * 8);
                a2[i] = *(const bf16x8*)(&kvs[row * 64 + cs]);
            }
#pragma unroll
            for (int j = 0; j < 4; j++) {
                const int row = 256 + wc * 64 + j * 16 + fr;
                const int cs = (kk * 32 + fkq * 8) ^ ((row & 7) * 8);
                b2v[j] = *(const bf16x8*)(&kvs[row * 64 + cs]);
            }
#pragma unroll
            for (int i = 0; i < 4; i++)
#pragma unroll
                for (int j = 0; j < 4; j++)
                    acc[i][j] = mfma16(a2[i], b2v[j], acc[i][j]);
        }
        __syncthreads();   // GEMM2 done reading kvs; next iter may overwrite
    }

    // epilogue: plain store of ctx partial tile [256c x 128d]
    float* cpb = cp + ((size_t)((b * 2 + h) * 16 + chunk)) * 256 * 128;
#pragma unroll
    for (int i = 0; i < 4; i++) {
        const int gc = wr * 64 + i * 16 + fkq * 4;
#pragma unroll
        for (int j = 0; j < 4; j++) {
            const int gd = wc * 64 + j * 16 + fr;
#pragma unroll
            for (int r = 0; r < 4; r++)
                cpb[(size_t)(gc + r) * 128 + gd] = acc[i][j][r];
        }
    }
    // rsum partials (only the h==0 half contributes, else doubled)
    if (h == 0) {
#pragma unroll
        for (int slot = 0; slot < 2; slot++)
#pragma unroll
            for (int r = 0; r < 4; r++) {
                float sv = rsacc[slot][r];
                sv += __shfl_xor(sv, 1, 64);
                sv += __shfl_xor(sv, 2, 64);
                sv += __shfl_xor(sv, 4, 64);
                sv += __shfl_xor(sv, 8, 64);
                if (fr == 0)
                    atomicAdd(&rsum[b * 256 + (slot * 8 + wave) * 16 + fkq * 4 + r], sv);
            }
    }
}

// ---------------------------------------------------------------------------
// K4r: ctx[b][c][h*128+d] = sum over 16 n-chunk partials of cp.
// grid 512 x 256 threads, one float4 per thread.
// ---------------------------------------------------------------------------
__global__ __launch_bounds__(256) void k4r_reduce(const float* __restrict__ cp,
                                                  float* __restrict__ ctx) {
    const int gid = blockIdx.x * 256 + threadIdx.x;   // 0..131071
    const int d4 = gid & 31;
    const int c  = (gid >> 5) & 255;
    const int h  = (gid >> 13) & 1;
    const int b  = gid >> 14;
    const float* src = cp + ((size_t)((b * 2 + h) * 16) * 256 + c) * 128 + d4 * 4;
    f32x4 s = {0.f, 0.f, 0.f, 0.f};
#pragma unroll
    for (int k = 0; k < 16; k++)
        s = s + *(const f32x4*)(src + (size_t)k * 32768);
    *(f32x4*)(ctx + ((size_t)b * 256 + c) * 256 + h * 128 + d4 * 4) = s;
}

// ---------------------------------------------------------------------------
// K5a: T[b,o,c] = (sum_d Wp[o,d]*ctx[b,c,d]) / rsum[b,c]   (fp32 tiled)
// grid (4,4,8) : 64x64 tiles
// ---------------------------------------------------------------------------
__global__ __launch_bounds__(256) void k5a_T(const float* __restrict__ Wp,
                                             const float* __restrict__ ctx,
                                             const float* __restrict__ rsum,
                                             float* __restrict__ T) {
    __shared__ float Asm[64][65];
    __shared__ float Bsm[64][65];
    const int b = blockIdx.z;
    const int o0 = blockIdx.y * 64, c0 = blockIdx.x * 64;
    const int t = threadIdx.x;
    const int tm = t >> 4, tn = t & 15;
    const int lc4 = tn * 4;
    float acc[4][4] = {};
    const float* cb = ctx + (size_t)b * C_ * C_;
    for (int kk = 0; kk < 256; kk += 64) {
        __syncthreads();
#pragma unroll
        for (int p = 0; p < 4; p++) {
            const int r = p * 16 + tm;
            const float4 av = *(const float4*)(Wp + (size_t)(o0 + r) * C_ + kk + lc4);
            Asm[r][lc4] = av.x; Asm[r][lc4 + 1] = av.y; Asm[r][lc4 + 2] = av.z; Asm[r][lc4 + 3] = av.w;
            const float4 bv = *(const float4*)(cb + (size_t)(c0 + r) * C_ + kk + lc4);
            Bsm[r][lc4] = bv.x; Bsm[r][lc4 + 1] = bv.y; Bsm[r][lc4 + 2] = bv.z; Bsm[r][lc4 + 3] = bv.w;
        }
        __syncthreads();
        for (int k = 0; k < 64; k++) {
            float a_[4], b_[4];
#pragma unroll
            for (int i = 0; i < 4; i++) a_[i] = Asm[tm * 4 + i][k];
#pragma unroll
            for (int j = 0; j < 4; j++) b_[j] = Bsm[tn * 4 + j][k];
#pragma unroll
            for (int i = 0; i < 4; i++)
#pragma unroll
                for (int j = 0; j < 4; j++) acc[i][j] += a_[i] * b_[j];
        }
    }
    float isv[4];
#pragma unroll
    for (int j = 0; j < 4; j++) isv[j] = 1.f / rsum[b * 256 + c0 + tn * 4 + j];
#pragma unroll
    for (int i = 0; i < 4; i++)
#pragma unroll
        for (int j = 0; j < 4; j++)
            T[((size_t)b * C_ + o0 + tm * 4 + i) * C_ + c0 + tn * 4 + j] = acc[i][j] * isv[j];
}

// ---------------------------------------------------------------------------
// K5b: G[b,o,j] = inv[o] * sum_c T[b,o,c]*Wq[c,j]   -> bf16  (fp32 tiled)
// grid (4,4,8)
// ---------------------------------------------------------------------------
__global__ __launch_bounds__(256) void k5b_G(const float* __restrict__ Tm,
                                             const float* __restrict__ Wq,
                                             const float* __restrict__ inv,
                                             unsigned short* __restrict__ G) {
    __shared__ float Asm[64][65];   // T rows o, cols c (k)
    __shared__ float Bsm[64][65];   // Wq rows c (k), cols j
    const int b = blockIdx.z;
    const int o0 = blockIdx.y * 64, j0 = blockIdx.x * 64;
    const int t = threadIdx.x;
    const int tm = t >> 4, tn = t & 15;
    const int lc4 = tn * 4;
    float acc[4][4] = {};
    const float* Tb = Tm + (size_t)b * C_ * C_;
    for (int kk = 0; kk < 256; kk += 64) {
        __syncthreads();
#pragma unroll
        for (int p = 0; p < 4; p++) {
            const int r = p * 16 + tm;
            const float4 av = *(const float4*)(Tb + (size_t)(o0 + r) * C_ + kk + lc4);
            Asm[r][lc4] = av.x; Asm[r][lc4 + 1] = av.y; Asm[r][lc4 + 2] = av.z; Asm[r][lc4 + 3] = av.w;
            const float4 bv = *(const float4*)(Wq + (size_t)(kk + r) * C_ + j0 + lc4);
            Bsm[r][lc4] = bv.x; Bsm[r][lc4 + 1] = bv.y; Bsm[r][lc4 + 2] = bv.z; Bsm[r][lc4 + 3] = bv.w;
        }
        __syncthreads();
        for (int k = 0; k < 64; k++) {
            float a_[4], b_[4];
#pragma unroll
            for (int i = 0; i < 4; i++) a_[i] = Asm[tm * 4 + i][k];
#pragma unroll
            for (int j = 0; j < 4; j++) b_[j] = Bsm[k][tn * 4 + j];
#pragma unroll
            for (int i = 0; i < 4; i++)
#pragma unroll
                for (int j = 0; j < 4; j++) acc[i][j] += a_[i] * b_[j];
        }
    }
#pragma unroll
    for (int i = 0; i < 4; i++) {
        const float iv = inv[o0 + tm * 4 + i];
#pragma unroll
        for (int j = 0; j < 4; j++)
            G[((size_t)b * C_ + o0 + tm * 4 + i) * C_ + j0 + tn * 4 + j] = f2bf(acc[i][j] * iv);
    }
}

// ---------------------------------------------------------------------------
// K6: out[b,o,n] = relu( sum_j G[b,o,j]*xT[b,n,j] + b2[o] )  fp32 out
// grid (128 n-tiles, 2 m-tiles, 8)
// ---------------------------------------------------------------------------
__global__ __launch_bounds__(256) void k6_out(const unsigned short* __restrict__ G,
                                              const unsigned short* __restrict__ xT,
                                              const float* __restrict__ b2,
                                              float* __restrict__ out) {
    __shared__ __align__(16) unsigned short As[128 * 32];
    __shared__ __align__(16) unsigned short Bs[128 * 32];
    const int b  = blockIdx.z;
    const int m0 = blockIdx.y * 128;
    const int n0 = blockIdx.x * 128;
    const int t = threadIdx.x, wave = t >> 6, lane = t & 63;
    const int wm = wave >> 1, wn = wave & 1;

    const unsigned short* Gb  = G  + (size_t)b * C_ * C_;
    const unsigned short* xTb = xT + (size_t)b * N_ * C_;

    const int ch1 = wave * 64 + lane, ch2 = ch1 + 256;
    const int r1 = ch1 >> 2, q1 = ch1 & 3;
    const int r2 = ch2 >> 2, q2 = ch2 & 3;
    unsigned short* ldsA1 = As + wave * 512;
    unsigned short* ldsA2 = As + 2048 + wave * 512;
    unsigned short* ldsB1 = Bs + wave * 512;
    unsigned short* ldsB2 = Bs + 2048 + wave * 512;

    f32x4 acc[4][4];
#pragma unroll
    for (int i = 0; i < 4; i++)
#pragma unroll
        for (int j = 0; j < 4; j++)
#pragma unroll
            for (int r = 0; r < 4; r++) acc[i][j][r] = 0.f;

    const int fr = lane & 15;
    const int fk = (lane >> 4) * 8;

    for (int kk = 0; kk < 256; kk += 32) {
        __syncthreads();
        gl_lds16(Gb  + (size_t)(m0 + r1) * 256 + kk + q1 * 8, ldsA1);
        gl_lds16(Gb  + (size_t)(m0 + r2) * 256 + kk + q2 * 8, ldsA2);
        gl_lds16(xTb + (size_t)(n0 + r1) * 256 + kk + q1 * 8, ldsB1);
        gl_lds16(xTb + (size_t)(n0 + r2) * 256 + kk + q2 * 8, ldsB2);
        __syncthreads();
        bf16x8 af[4], bfv[4];
#pragma unroll
        for (int i = 0; i < 4; i++)
            af[i] = *(const bf16x8*)(As + (wm * 64 + i * 16 + fr) * 32 + fk);
#pragma unroll
        for (int j = 0; j < 4; j++)
            bfv[j] = *(const bf16x8*)(Bs + (wn * 64 + j * 16 + fr) * 32 + fk);
#pragma unroll
        for (int i = 0; i < 4; i++)
#pragma unroll
            for (int j = 0; j < 4; j++)
                acc[i][j] = mfma16(af[i], bfv[j], acc[i][j]);
    }

    const int col = lane & 15, rowq = (lane >> 4) * 4;
    float* ob = out + (size_t)b * C_ * N_;
#pragma unroll
    for (int i = 0; i < 4; i++) {
        const int gm = m0 + wm * 64 + i * 16 + rowq;
#pragma unroll
        for (int j = 0; j < 4; j++) {
            const int gn = n0 + wn * 64 + j * 16 + col;
#pragma unroll
            for (int r = 0; r < 4; r++) {
                const float val = fmaxf(acc[i][j][r] + b2[gm + r], 0.f);
                ob[(size_t)(gm + r) * N_ + gn] = val;
            }
        }
    }
}

// ---------------------------------------------------------------------------
extern "C" void kernel_launch(void* const* d_in, const int* in_sizes, int n_in,
                              void* d_out, int out_size, void* d_ws, size_t ws_size,
                              hipStream_t stream) {
    const float* x     = (const float*)d_in[0];
    const float* wqkv  = (const float*)d_in[1];
    const float* wproj = (const float*)d_in[2];
    const float* gamma = (const float*)d_in[3];
    const float* beta  = (const float*)d_in[4];
    const float* rmean = (const float*)d_in[5];
    const float* rvar  = (const float*)d_in[6];
    float* out = (float*)d_out;

    char* ws = (char*)d_ws;
    size_t off = 0;
    auto alloc = [&](size_t bytes) {
        void* p = ws + off;
        off += (bytes + 255) & ~(size_t)255;
        return p;
    };
    unsigned short* xT   = (unsigned short*)alloc((size_t)B_ * N_ * C_ * 2);  // 64 MiB
    unsigned short* WkvF = (unsigned short*)alloc((size_t)512 * 256 * 2);     // 256 KiB
    float* invp = (float*)alloc(256 * 4);
    float* b2p  = (float*)alloc(256 * 4);
    float* cp   = (float*)alloc((size_t)256 * 256 * 128 * 4);  // 32 MiB partials
    float* ctx  = (float*)alloc((size_t)B_ * C_ * C_ * 4);     // 2 MiB
    float* rsum = (float*)alloc(2048 * 4);
    float* Tm   = (float*)alloc((size_t)B_ * C_ * C_ * 4);     // 2 MiB
    unsigned short* G = (unsigned short*)alloc((size_t)B_ * C_ * C_ * 2);

    hipLaunchKernelGGL(k1_transpose, dim3(256, 4, 8), dim3(256), 0, stream, x, xT);
    hipLaunchKernelGGL(k1b_setup, dim3(65), dim3(256), 0, stream,
                       wqkv, gamma, beta, rmean, rvar, WkvF, invp, b2p);
    hipMemsetAsync(rsum, 0, 2048 * 4, stream);
    hipLaunchKernelGGL(k2_ctx, dim3(16, 2, 8), dim3(512), 0, stream, WkvF, xT, cp, rsum);
    hipLaunchKernelGGL(k4r_reduce, dim3(512), dim3(256), 0, stream, cp, ctx);
    hipLaunchKernelGGL(k5a_T, dim3(4, 4, 8), dim3(256), 0, stream, wproj, ctx, rsum, Tm);
    hipLaunchKernelGGL(k5b_G, dim3(4, 4, 8), dim3(256), 0, stream, Tm, wqkv, invp, G);
    hipLaunchKernelGGL(k6_out, dim3(128, 2, 8), dim3(256), 0, stream, G, xT, b2p, out);
}

// Round 4
// 381.504 us; speedup vs baseline: 1.5273x; 1.0073x over previous
//
#include <hip/hip_runtime.h>
#include <stdint.h>

// Problem constants
#define B_   8
#define C_   256
#define N_   16384   // 128*128 spatial

#define NS    32     // k2 n-subchunk
#define KVP   40     // kvs row stride in shorts (80 B -> conflict-free, no XOR)

typedef __attribute__((ext_vector_type(8))) short bf16x8;
typedef __attribute__((ext_vector_type(4))) float f32x4;

__device__ inline float bf2f(unsigned short h) {
    return __uint_as_float(((unsigned)h) << 16);
}
__device__ inline unsigned short f2bf(float f) {
    unsigned u = __float_as_uint(f);
    u += 0x7FFF + ((u >> 16) & 1);   // round-to-nearest-even
    return (unsigned short)(u >> 16);
}
// pack two f32 -> two bf16 in one dword (single VALU instr)
__device__ inline unsigned cvt_pk_bf16(float lo, float hi) {
    unsigned r;
    asm("v_cvt_pk_bf16_f32 %0, %1, %2" : "=v"(r) : "v"(lo), "v"(hi));
    return r;
}

// async global->LDS, 16B per lane. LDS dest = wave-uniform base + lane*16.
__device__ inline void gl_lds16(const void* g, void* l) {
    __builtin_amdgcn_global_load_lds(
        reinterpret_cast<const __attribute__((address_space(1))) unsigned int*>(
            reinterpret_cast<uintptr_t>(g)),
        reinterpret_cast<__attribute__((address_space(3))) unsigned int*>(
            reinterpret_cast<uintptr_t>(l)),
        16, 0, 0);
}

__device__ inline f32x4 mfma16(bf16x8 a, bf16x8 b, f32x4 c) {
    return __builtin_amdgcn_mfma_f32_16x16x32_bf16(a, b, c, 0, 0, 0);
}

// ---------------------------------------------------------------------------
// K1: x [B,C,N] fp32  ->  xT [B,N,C] bf16   (64x64 tiles through LDS)
// ---------------------------------------------------------------------------
__global__ __launch_bounds__(256) void k1_transpose(const float* __restrict__ x,
                                                    unsigned short* __restrict__ xT) {
    __shared__ unsigned short tile[64][65];
    const int b = blockIdx.z, c0 = blockIdx.y * 64, n0 = blockIdx.x * 64;
    const float* xb = x + (size_t)b * C_ * N_;
    const int t = threadIdx.x;
    const int tr = t >> 4, tc4 = (t & 15) * 4;
#pragma unroll
    for (int p = 0; p < 4; p++) {
        const int i = p * 16 + tr;   // c index
        const float4 v = *(const float4*)(xb + (size_t)(c0 + i) * N_ + n0 + tc4);
        tile[i][tc4 + 0] = f2bf(v.x);
        tile[i][tc4 + 1] = f2bf(v.y);
        tile[i][tc4 + 2] = f2bf(v.z);
        tile[i][tc4 + 3] = f2bf(v.w);
    }
    __syncthreads();
    unsigned short* xTb = xT + (size_t)b * N_ * C_;
#pragma unroll
    for (int p = 0; p < 4; p++) {
        const int jj = p * 16 + tr;  // n index
        ushort4 o;
        o.x = tile[tc4 + 0][jj];
        o.y = tile[tc4 + 1][jj];
        o.z = tile[tc4 + 2][jj];
        o.w = tile[tc4 + 3][jj];
        *(ushort4*)(xTb + (size_t)(n0 + jj) * C_ + c0 + tc4) = o;
    }
}

// ---------------------------------------------------------------------------
// K1b: blocks 0..63: pack w_kv (wqkv rows 256..767) into fragment-major bf16.
//      block 64: BN constants + zero rsum (replaces separate memset).
// ---------------------------------------------------------------------------
__global__ __launch_bounds__(256) void k1b_setup(const float* __restrict__ wqkv,
                                                 const float* __restrict__ gamma,
                                                 const float* __restrict__ beta,
                                                 const float* __restrict__ rmean,
                                                 const float* __restrict__ rvar,
                                                 unsigned short* __restrict__ WkvF,
                                                 float* __restrict__ inv,
                                                 float* __restrict__ b2,
                                                 float* __restrict__ rsum) {
    const int t = threadIdx.x;
    if (blockIdx.x < 64) {
        const int chunk = blockIdx.x * 256 + t;   // 16384 chunks of 8 shorts
        const int lane = chunk & 63;
        const int kb = (chunk >> 6) & 7;
        const int rb = chunk >> 9;                // 0..31
        const int row = rb * 16 + (lane & 15);    // 0..511 (kv row)
        const int k0 = kb * 32 + (lane >> 4) * 8;
        const float* src = wqkv + (size_t)(256 + row) * 256 + k0;
        const float4 a = *(const float4*)(src);
        const float4 c = *(const float4*)(src + 4);
        ushort4 o0, o1;
        o0.x = f2bf(a.x); o0.y = f2bf(a.y); o0.z = f2bf(a.z); o0.w = f2bf(a.w);
        o1.x = f2bf(c.x); o1.y = f2bf(c.y); o1.z = f2bf(c.z); o1.w = f2bf(c.w);
        *(ushort4*)(WkvF + (size_t)chunk * 8) = o0;
        *(ushort4*)(WkvF + (size_t)chunk * 8 + 4) = o1;
    } else {
        const float iv = gamma[t] * rsqrtf(rvar[t] + 1e-5f);
        inv[t] = iv;
        b2[t]  = beta[t] - rmean[t] * iv;
        float4 z = {0.f, 0.f, 0.f, 0.f};
        *(float4*)(rsum + t * 8)     = z;
        *(float4*)(rsum + t * 8 + 4) = z;
    }
}

// ---------------------------------------------------------------------------
// K2: FUSED kv-GEMM + exp + context GEMM, d-split, W in registers, SWAPPED
//     GEMM1 operands: C[row=n, col=kvrow] so each lane's 4 acc values are 4
//     consecutive n at one kv-row -> cvt_pk_bf16 pairs + ds_write_b64 into
//     kvs[kvrow][n] (row stride 40 shorts = 80B: conflict-free, no XOR).
//  Block = (n-chunk of 512, d-half h, batch b). 16 subchunks of 32 n.
//  grid (32, 2, 8) = 512 blocks, 512 thr, LDS 63 KiB -> 2 blocks/CU.
// ---------------------------------------------------------------------------
__global__ __launch_bounds__(512, 2) void k2_ctx(const unsigned short* __restrict__ WkvF,
                                                 const unsigned short* __restrict__ xT,
                                                 float* __restrict__ cp,
                                                 float* __restrict__ rsum) {
    __shared__ __align__(16) unsigned short xs[2][NS * 256];   // 2 x 16 KiB
    __shared__ __align__(16) unsigned short kvs[384 * KVP];    // 30 KiB
    const int chunk = blockIdx.x;
    const int h  = blockIdx.y;
    const int b  = blockIdx.z;
    const int n0 = chunk * 512;
    const int t = threadIdx.x, wave = t >> 6, lane = t & 63;
    const int fr = lane & 15, fkq = lane >> 4;                 // frag row / k-quad
    const int wr = wave >> 1, wc = wave & 1;                   // ctx wave grid 4x2
    const unsigned short* xTb = xT + (size_t)b * N_ * C_;

    // persistent W fragments: 3 rowblocks x 8 kb = 24 x bf16x8 (96 VGPR).
    //   slot0: k rowblk wave, slot1: k rowblk 8+wave, slot2: v rowblk 16+h*8+wave
    bf16x8 wf[3][8];
    {
        const int rbs[3] = {wave, 8 + wave, 16 + h * 8 + wave};
#pragma unroll
        for (int slot = 0; slot < 3; slot++)
#pragma unroll
            for (int kb = 0; kb < 8; kb++)
                wf[slot][kb] = *(const bf16x8*)(
                    WkvF + (((size_t)rbs[slot] * 8 + kb) * 64 + lane) * 8);
    }
    // kvs row bases per slot (kvs rows: 0..255 = k logits, 256..383 = v half)
    const int rowbase[3] = {wave * 16, 128 + wave * 16, 256 + wave * 16};

    f32x4 acc[4][4];                 // ctx tile 64c x 64d per wave
#pragma unroll
    for (int i = 0; i < 4; i++)
#pragma unroll
        for (int j = 0; j < 4; j++)
#pragma unroll
            for (int r = 0; r < 4; r++) acc[i][j][r] = 0.f;
    float rsacc[2] = {0.f, 0.f};     // row-sum partials (k slots)

    // stage subchunk sc (32 n-rows x 256 c) into xs[buf]; LDS linear,
    // global source columns inverse-swizzled: xs[r*256+c] = xT[nb+r][c ^ ((r&7)*8)]
    auto stage = [&](int buf, int sc) {
        const int nb = n0 + sc * NS;
#pragma unroll
        for (int it = 0; it < 2; it++) {
            const int idx = it * 512 + t;        // 16B-chunk id, 0..1023
            const int r = idx >> 5;              // n row 0..31
            const int c = (idx & 31) * 8;        // c col (short units)
            const int csw = c ^ ((r & 7) * 8);
            gl_lds16(xTb + (size_t)(nb + r) * 256 + csw,
                     &xs[buf][it * 4096 + wave * 512]);
        }
    };

    stage(0, 0);
    __syncthreads();

    for (int s = 0; s < 16; ++s) {
        const int cur = s & 1;
        if (s < 15) stage(cur ^ 1, s + 1);       // prefetch next subchunk

        // GEMM1 (swapped): kacc[slot][jj] = x[n,:] . W[kvrow,:]
        f32x4 kacc[3][2];
#pragma unroll
        for (int i = 0; i < 3; i++)
#pragma unroll
            for (int j = 0; j < 2; j++)
#pragma unroll
                for (int r = 0; r < 4; r++) kacc[i][j][r] = 0.f;
#pragma unroll
        for (int kb = 0; kb < 8; kb++) {
            bf16x8 bfa[2];
#pragma unroll
            for (int jj = 0; jj < 2; jj++) {
                const int rr = jj * 16 + fr;     // n row
                const int cs = (kb * 32 + fkq * 8) ^ ((fr & 7) * 8);
                bfa[jj] = *(const bf16x8*)(&xs[cur][rr * 256 + cs]);
            }
#pragma unroll
            for (int slot = 0; slot < 3; slot++) {
                kacc[slot][0] = mfma16(bfa[0], wf[slot][kb], kacc[slot][0]);
                kacc[slot][1] = mfma16(bfa[1], wf[slot][kb], kacc[slot][1]);
            }
        }
        // exp on k slots + packed b64 writes to kvs[kvrow][n]
#pragma unroll
        for (int slot = 0; slot < 3; slot++) {
            const int kvrow = rowbase[slot] + fr;
#pragma unroll
            for (int jj = 0; jj < 2; jj++) {
                f32x4 v = kacc[slot][jj];
                if (slot < 2) {
                    v[0] = __expf(v[0]); v[1] = __expf(v[1]);
                    v[2] = __expf(v[2]); v[3] = __expf(v[3]);
                    rsacc[slot] += (v[0] + v[1]) + (v[2] + v[3]);
                }
                uint2 pk;
                pk.x = cvt_pk_bf16(v[0], v[1]);
                pk.y = cvt_pk_bf16(v[2], v[3]);
                *(uint2*)(&kvs[kvrow * KVP + jj * 16 + fkq * 4]) = pk;
            }
        }
        __syncthreads();   // kvs complete (also drains prefetch vmcnt)

        // GEMM2: ctx[64c x 64d] += expk[64c x 32n] * v[64d x 32n]^T  (K=32)
        {
            bf16x8 a2[4], b2v[4];
#pragma unroll
            for (int i = 0; i < 4; i++) {
                const int row = wr * 64 + i * 16 + fr;
                a2[i] = *(const bf16x8*)(&kvs[row * KVP + fkq * 8]);
            }
#pragma unroll
            for (int j = 0; j < 4; j++) {
                const int row = 256 + wc * 64 + j * 16 + fr;
                b2v[j] = *(const bf16x8*)(&kvs[row * KVP + fkq * 8]);
            }
#pragma unroll
            for (int i = 0; i < 4; i++)
#pragma unroll
                for (int j = 0; j < 4; j++)
                    acc[i][j] = mfma16(a2[i], b2v[j], acc[i][j]);
        }
        __syncthreads();   // GEMM2 done reading kvs; next iter may overwrite
    }

    // epilogue: plain store of ctx partial tile [256c x 128d]
    float* cpb = cp + ((size_t)((b * 2 + h) * 32 + chunk)) * 256 * 128;
#pragma unroll
    for (int i = 0; i < 4; i++) {
        const int gc = wr * 64 + i * 16 + fkq * 4;
#pragma unroll
        for (int j = 0; j < 4; j++) {
            const int gd = wc * 64 + j * 16 + fr;
#pragma unroll
            for (int r = 0; r < 4; r++)
                cpb[(size_t)(gc + r) * 128 + gd] = acc[i][j][r];
        }
    }
    // rsum partials (lane fr holds kvrow = base+fr after fkq-reduce)
    if (h == 0) {
#pragma unroll
        for (int slot = 0; slot < 2; slot++) {
            float sv = rsacc[slot];
            sv += __shfl_xor(sv, 16, 64);
            sv += __shfl_xor(sv, 32, 64);
            if (fkq == 0)
                atomicAdd(&rsum[b * 256 + slot * 128 + wave * 16 + fr], sv);
        }
    }
}

// ---------------------------------------------------------------------------
// K4r: ctx[b][c][h*128+d] = sum over 32 n-chunk partials of cp.
// grid 512 x 256 threads, one float4 per thread.
// ---------------------------------------------------------------------------
__global__ __launch_bounds__(256) void k4r_reduce(const float* __restrict__ cp,
                                                  float* __restrict__ ctx) {
    const int gid = blockIdx.x * 256 + threadIdx.x;   // 0..131071
    const int d4 = gid & 31;
    const int c  = (gid >> 5) & 255;
    const int h  = (gid >> 13) & 1;
    const int b  = gid >> 14;
    const float* src = cp + ((size_t)((b * 2 + h) * 32) * 256 + c) * 128 + d4 * 4;
    f32x4 s = {0.f, 0.f, 0.f, 0.f};
#pragma unroll
    for (int k = 0; k < 32; k++)
        s = s + *(const f32x4*)(src + (size_t)k * 32768);
    *(f32x4*)(ctx + ((size_t)b * 256 + c) * 256 + h * 128 + d4 * 4) = s;
}

// ---------------------------------------------------------------------------
// K5a: T[b,o,c] = (sum_d Wp[o,d]*ctx[b,c,d]) / rsum[b,c]   (fp32 tiled)
// grid (4,4,8) : 64x64 tiles
// ---------------------------------------------------------------------------
__global__ __launch_bounds__(256) void k5a_T(const float* __restrict__ Wp,
                                             const float* __restrict__ ctx,
                                             const float* __restrict__ rsum,
                                             float* __restrict__ T) {
    __shared__ float Asm[64][65];
    __shared__ float Bsm[64][65];
    const int b = blockIdx.z;
    const int o0 = blockIdx.y * 64, c0 = blockIdx.x * 64;
    const int t = threadIdx.x;
    const int tm = t >> 4, tn = t & 15;
    const int lc4 = tn * 4;
    float acc[4][4] = {};
    const float* cb = ctx + (size_t)b * C_ * C_;
    for (int kk = 0; kk < 256; kk += 64) {
        __syncthreads();
#pragma unroll
        for (int p = 0; p < 4; p++) {
            const int r = p * 16 + tm;
            const float4 av = *(const float4*)(Wp + (size_t)(o0 + r) * C_ + kk + lc4);
            Asm[r][lc4] = av.x; Asm[r][lc4 + 1] = av.y; Asm[r][lc4 + 2] = av.z; Asm[r][lc4 + 3] = av.w;
            const float4 bv = *(const float4*)(cb + (size_t)(c0 + r) * C_ + kk + lc4);
            Bsm[r][lc4] = bv.x; Bsm[r][lc4 + 1] = bv.y; Bsm[r][lc4 + 2] = bv.z; Bsm[r][lc4 + 3] = bv.w;
        }
        __syncthreads();
        for (int k = 0; k < 64; k++) {
            float a_[4], b_[4];
#pragma unroll
            for (int i = 0; i < 4; i++) a_[i] = Asm[tm * 4 + i][k];
#pragma unroll
            for (int j = 0; j < 4; j++) b_[j] = Bsm[tn * 4 + j][k];
#pragma unroll
            for (int i = 0; i < 4; i++)
#pragma unroll
                for (int j = 0; j < 4; j++) acc[i][j] += a_[i] * b_[j];
        }
    }
    float isv[4];
#pragma unroll
    for (int j = 0; j < 4; j++) isv[j] = 1.f / rsum[b * 256 + c0 + tn * 4 + j];
#pragma unroll
    for (int i = 0; i < 4; i++)
#pragma unroll
        for (int j = 0; j < 4; j++)
            T[((size_t)b * C_ + o0 + tm * 4 + i) * C_ + c0 + tn * 4 + j] = acc[i][j] * isv[j];
}

// ---------------------------------------------------------------------------
// K5b: G[b,o,j] = inv[o] * sum_c T[b,o,c]*Wq[c,j]   -> bf16  (fp32 tiled)
// grid (4,4,8)
// ---------------------------------------------------------------------------
__global__ __launch_bounds__(256) void k5b_G(const float* __restrict__ Tm,
                                             const float* __restrict__ Wq,
                                             const float* __restrict__ inv,
                                             unsigned short* __restrict__ G) {
    __shared__ float Asm[64][65];   // T rows o, cols c (k)
    __shared__ float Bsm[64][65];   // Wq rows c (k), cols j
    const int b = blockIdx.z;
    const int o0 = blockIdx.y * 64, j0 = blockIdx.x * 64;
    const int t = threadIdx.x;
    const int tm = t >> 4, tn = t & 15;
    const int lc4 = tn * 4;
    float acc[4][4] = {};
    const float* Tb = Tm + (size_t)b * C_ * C_;
    for (int kk = 0; kk < 256; kk += 64) {
        __syncthreads();
#pragma unroll
        for (int p = 0; p < 4; p++) {
            const int r = p * 16 + tm;
            const float4 av = *(const float4*)(Tb + (size_t)(o0 + r) * C_ + kk + lc4);
            Asm[r][lc4] = av.x; Asm[r][lc4 + 1] = av.y; Asm[r][lc4 + 2] = av.z; Asm[r][lc4 + 3] = av.w;
            const float4 bv = *(const float4*)(Wq + (size_t)(kk + r) * C_ + j0 + lc4);
            Bsm[r][lc4] = bv.x; Bsm[r][lc4 + 1] = bv.y; Bsm[r][lc4 + 2] = bv.z; Bsm[r][lc4 + 3] = bv.w;
        }
        __syncthreads();
        for (int k = 0; k < 64; k++) {
            float a_[4], b_[4];
#pragma unroll
            for (int i = 0; i < 4; i++) a_[i] = Asm[tm * 4 + i][k];
#pragma unroll
            for (int j = 0; j < 4; j++) b_[j] = Bsm[k][tn * 4 + j];
#pragma unroll
            for (int i = 0; i < 4; i++)
#pragma unroll
                for (int j = 0; j < 4; j++) acc[i][j] += a_[i] * b_[j];
        }
    }
#pragma unroll
    for (int i = 0; i < 4; i++) {
        const float iv = inv[o0 + tm * 4 + i];
#pragma unroll
        for (int j = 0; j < 4; j++)
            G[((size_t)b * C_ + o0 + tm * 4 + i) * C_ + j0 + tn * 4 + j] = f2bf(acc[i][j] * iv);
    }
}

// ---------------------------------------------------------------------------
// K6: out[b,o,n] = relu( sum_j G[b,o,j]*xT[b,n,j] + b2[o] )  fp32 out
// grid (128 n-tiles, 2 m-tiles, 8)
// ---------------------------------------------------------------------------
__global__ __launch_bounds__(256) void k6_out(const unsigned short* __restrict__ G,
                                              const unsigned short* __restrict__ xT,
                                              const float* __restrict__ b2,
                                              float* __restrict__ out) {
    __shared__ __align__(16) unsigned short As[128 * 32];
    __shared__ __align__(16) unsigned short Bs[128 * 32];
    const int b  = blockIdx.z;
    const int m0 = blockIdx.y * 128;
    const int n0 = blockIdx.x * 128;
    const int t = threadIdx.x, wave = t >> 6, lane = t & 63;
    const int wm = wave >> 1, wn = wave & 1;

    const unsigned short* Gb  = G  + (size_t)b * C_ * C_;
    const unsigned short* xTb = xT + (size_t)b * N_ * C_;

    const int ch1 = wave * 64 + lane, ch2 = ch1 + 256;
    const int r1 = ch1 >> 2, q1 = ch1 & 3;
    const int r2 = ch2 >> 2, q2 = ch2 & 3;
    unsigned short* ldsA1 = As + wave * 512;
    unsigned short* ldsA2 = As + 2048 + wave * 512;
    unsigned short* ldsB1 = Bs + wave * 512;
    unsigned short* ldsB2 = Bs + 2048 + wave * 512;

    f32x4 acc[4][4];
#pragma unroll
    for (int i = 0; i < 4; i++)
#pragma unroll
        for (int j = 0; j < 4; j++)
#pragma unroll
            for (int r = 0; r < 4; r++) acc[i][j][r] = 0.f;

    const int fr = lane & 15;
    const int fk = (lane >> 4) * 8;

    for (int kk = 0; kk < 256; kk += 32) {
        __syncthreads();
        gl_lds16(Gb  + (size_t)(m0 + r1) * 256 + kk + q1 * 8, ldsA1);
        gl_lds16(Gb  + (size_t)(m0 + r2) * 256 + kk + q2 * 8, ldsA2);
        gl_lds16(xTb + (size_t)(n0 + r1) * 256 + kk + q1 * 8, ldsB1);
        gl_lds16(xTb + (size_t)(n0 + r2) * 256 + kk + q2 * 8, ldsB2);
        __syncthreads();
        bf16x8 af[4], bfv[4];
#pragma unroll
        for (int i = 0; i < 4; i++)
            af[i] = *(const bf16x8*)(As + (wm * 64 + i * 16 + fr) * 32 + fk);
#pragma unroll
        for (int j = 0; j < 4; j++)
            bfv[j] = *(const bf16x8*)(Bs + (wn * 64 + j * 16 + fr) * 32 + fk);
#pragma unroll
        for (int i = 0; i < 4; i++)
#pragma unroll
            for (int j = 0; j < 4; j++)
                acc[i][j] = mfma16(af[i], bfv[j], acc[i][j]);
    }

    const int col = lane & 15, rowq = (lane >> 4) * 4;
    float* ob = out + (size_t)b * C_ * N_;
#pragma unroll
    for (int i = 0; i < 4; i++) {
        const int gm = m0 + wm * 64 + i * 16 + rowq;
#pragma unroll
        for (int j = 0; j < 4; j++) {
            const int gn = n0 + wn * 64 + j * 16 + col;
#pragma unroll
            for (int r = 0; r < 4; r++) {
                const float val = fmaxf(acc[i][j][r] + b2[gm + r], 0.f);
                ob[(size_t)(gm + r) * N_ + gn] = val;
            }
        }
    }
}

// ---------------------------------------------------------------------------
extern "C" void kernel_launch(void* const* d_in, const int* in_sizes, int n_in,
                              void* d_out, int out_size, void* d_ws, size_t ws_size,
                              hipStream_t stream) {
    const float* x     = (const float*)d_in[0];
    const float* wqkv  = (const float*)d_in[1];
    const float* wproj = (const float*)d_in[2];
    const float* gamma = (const float*)d_in[3];
    const float* beta  = (const float*)d_in[4];
    const float* rmean = (const float*)d_in[5];
    const float* rvar  = (const float*)d_in[6];
    float* out = (float*)d_out;

    char* ws = (char*)d_ws;
    size_t off = 0;
    auto alloc = [&](size_t bytes) {
        void* p = ws + off;
        off += (bytes + 255) & ~(size_t)255;
        return p;
    };
    unsigned short* xT   = (unsigned short*)alloc((size_t)B_ * N_ * C_ * 2);  // 64 MiB
    unsigned short* WkvF = (unsigned short*)alloc((size_t)512 * 256 * 2);     // 256 KiB
    float* invp = (float*)alloc(256 * 4);
    float* b2p  = (float*)alloc(256 * 4);
    float* cp   = (float*)alloc((size_t)512 * 256 * 128 * 4);  // 64 MiB partials
    float* ctx  = (float*)alloc((size_t)B_ * C_ * C_ * 4);     // 2 MiB
    float* rsum = (float*)alloc(2048 * 4);
    float* Tm   = (float*)alloc((size_t)B_ * C_ * C_ * 4);     // 2 MiB
    unsigned short* G = (unsigned short*)alloc((size_t)B_ * C_ * C_ * 2);

    hipLaunchKernelGGL(k1_transpose, dim3(256, 4, 8), dim3(256), 0, stream, x, xT);
    hipLaunchKernelGGL(k1b_setup, dim3(65), dim3(256), 0, stream,
                       wqkv, gamma, beta, rmean, rvar, WkvF, invp, b2p, rsum);
    hipLaunchKernelGGL(k2_ctx, dim3(32, 2, 8), dim3(512), 0, stream, WkvF, xT, cp, rsum);
    hipLaunchKernelGGL(k4r_reduce, dim3(512), dim3(256), 0, stream, cp, ctx);
    hipLaunchKernelGGL(k5a_T, dim3(4, 4, 8), dim3(256), 0, stream, wproj, ctx, rsum, Tm);
    hipLaunchKernelGGL(k5b_G, dim3(4, 4, 8), dim3(256), 0, stream, Tm, wqkv, invp, G);
    hipLaunchKernelGGL(k6_out, dim3(128, 2, 8), dim3(256), 0, stream, G, xT, b2p, out);
}